// Round 8
// baseline (175.026 us; speedup 1.0000x reference)
//
#include <hip/hip_runtime.h>
#include <hip/hip_bf16.h>
#include <math.h>

#define BN 8192
#define DK 128
#define NSPLIT 32
#define JR (BN / NSPLIT)   // 256
#define NJS (JR / 64)      // 4
#define MARGIN_F 1.0f
#define I32MIN (-2147483647 - 1)
#define I32MAX 2147483647

// ---------------- workspace layout (float-slot offsets from d_ws) -------------
// Eb  : bf16 8192x128 (B-side)            = 2MB = 524288 slots
// EbS : bf16 8192x128 scaled by -128 (A)  = 2MB
// sq64: f32 64*rowsq
// posP/negP: i32 [NSPLIT][BN] packed
// loss: f32 [BN]
#define OFF_EBS  524288
#define OFF_SQ   1048576
#define OFF_POSP (OFF_SQ + BN)
#define OFF_NEGP (OFF_POSP + NSPLIT * BN)
#define OFF_LOSS (OFF_NEGP + NSPLIT * BN)

typedef __attribute__((ext_vector_type(8))) short bf16x8;
typedef __attribute__((ext_vector_type(4))) float f32x4;

__device__ __forceinline__ unsigned short f2bf(float f) {
    __hip_bfloat16 h = __float2bfloat16(f);
    return *reinterpret_cast<unsigned short*>(&h);
}
__device__ __forceinline__ int imax(int a, int b) { return a > b ? a : b; }
__device__ __forceinline__ int imin(int a, int b) { return a < b ? a : b; }

__device__ __forceinline__ void gload_lds16(const void* g, void* s) {
    __builtin_amdgcn_global_load_lds(
        (const __attribute__((address_space(1))) void*)g,
        (__attribute__((address_space(3))) void*)s, 16, 0, 0);
}

// ---------------- prep: bf16 tables (plain + -128-scaled) + 64*rowsq ----------
__global__ __launch_bounds__(256) void k_prep(const float* __restrict__ emb,
                                              unsigned short* __restrict__ Eb,
                                              unsigned short* __restrict__ EbS,
                                              float* __restrict__ sq64) {
    int row  = blockIdx.x * 4 + (threadIdx.x >> 6);
    int lane = threadIdx.x & 63;
    float2 v = ((const float2*)(emb + (size_t)row * DK))[lane];
    ushort2 o;  o.x  = f2bf(v.x);           o.y  = f2bf(v.y);
    ushort2 os; os.x = f2bf(v.x * -128.0f); os.y = f2bf(v.y * -128.0f);
    ((ushort2*)(Eb  + (size_t)row * DK))[lane] = o;
    ((ushort2*)(EbS + (size_t)row * DK))[lane] = os;
    float s = v.x * v.x + v.y * v.y;
    #pragma unroll
    for (int m = 32; m; m >>= 1) s += __shfl_xor(s, m);
    if (lane == 0) sq64[row] = 64.0f * s;
}

// ---------------- fused MFMA Gram + batch-hard mining -------------------------
// Block = 4 waves sharing one 64-row i-tile (A panel in 16KB LDS, staged once,
// XOR-swizzled, read-only -> single barrier). Each wave owns one j-split of
// 256 cols (NSPLIT=32 -> 1024 blocks = 4 blocks/CU supplied). acc split into
// two ni-passes (acc[4][2]) so peak VGPR ~112 < 128 -> 4 waves/SIMD resident
// (round-7 lesson: VGPR=128 still caps at 2 waves/SIMD).
// A is pre-scaled by -128, C-init = 64*sq_j  =>  acc = 64*(sq_j - 2 dot).
// Packed-i32 mining: pos=max((k<<13)|(8191-j)), neg=min((k<<13)|j).
__global__ __launch_bounds__(256, 4)
void k_mine3(const unsigned short* __restrict__ Eb,
             const unsigned short* __restrict__ EbS,
             const float* __restrict__ sq64,
             const int* __restrict__ tgt,
             int* __restrict__ posP, int* __restrict__ negP) {
    __shared__ __align__(16) char Alds[16384];

    const int tid = threadIdx.x;
    const int w   = tid >> 6;
    const int l   = tid & 63;
    const int gw  = blockIdx.x * 4 + w;
    const int itile = gw >> 5;            // same for all 4 waves of a block
    const int split = gw & 31;
    const int i0 = itile * 64;
    const int jb = split * JR;
    const int lh = l >> 4;
    const int tx = l & 15;
    const char* EbB = (const char*)Eb;

    // stage A panel (64 rows x 256B of EbS) into LDS, source-swizzled:
    // LDS[row][c] = EbS[i0+row][c ^ (row&7)]   (c = 16B chunk)
    {
        const char* S = (const char*)(EbS + (size_t)i0 * DK);
        #pragma unroll
        for (int q = 0; q < 4; ++q) {
            int f   = tid + 256 * q;          // 0..1023
            int row = f >> 4;
            int sc  = (f & 15) ^ (row & 7);
            gload_lds16(S + row * 256 + sc * 16, Alds + w * 1024 + q * 4096);
        }
    }
    asm volatile("s_waitcnt vmcnt(0)" ::: "memory");
    __syncthreads();

    // packed i-targets (<64): byte v of tpk[mi] = tgt[i0 + mi*16 + lh*4 + v]
    int tpk[4];
    #pragma unroll
    for (int mi = 0; mi < 4; ++mi) {
        int4 q = *(const int4*)(tgt + i0 + mi * 16 + lh * 4);
        tpk[mi] = q.x | (q.y << 8) | (q.z << 16) | (q.w << 24);
    }

    int pp[16], nn[16];
    #pragma unroll
    for (int r = 0; r < 16; ++r) { pp[r] = I32MIN; nn[r] = I32MAX; }

    for (int js = 0; js < NJS; ++js) {
        const int j0 = jb + js * 64;
        #pragma unroll
        for (int pass = 0; pass < 2; ++pass) {
            int jn[2], jc[2], tj[2]; float sqj[2];
            #pragma unroll
            for (int u = 0; u < 2; ++u) {
                int j = j0 + (pass * 2 + u) * 16 + tx;
                jn[u] = j; jc[u] = 8191 - j;
                sqj[u] = sq64[j]; tj[u] = tgt[j];
            }

            f32x4 acc[4][2];
            #pragma unroll
            for (int mi = 0; mi < 4; ++mi)
                #pragma unroll
                for (int u = 0; u < 2; ++u) {
                    f32x4 a0 = {sqj[u], sqj[u], sqj[u], sqj[u]};
                    acc[mi][u] = a0;
                }

            #pragma unroll
            for (int ks = 0; ks < 4; ++ks) {
                bf16x8 Bf[2];
                #pragma unroll
                for (int u = 0; u < 2; ++u)
                    Bf[u] = *(const bf16x8*)(EbB + (size_t)jn[u] * 256 + ks * 64 + lh * 16);
                bf16x8 Af[4];
                #pragma unroll
                for (int mi = 0; mi < 4; ++mi) {
                    int row = mi * 16 + tx;
                    int c   = (ks * 4 + lh) ^ (row & 7);
                    Af[mi] = *(const bf16x8*)(Alds + row * 256 + c * 16);
                }
                #pragma unroll
                for (int mi = 0; mi < 4; ++mi)
                    #pragma unroll
                    for (int u = 0; u < 2; ++u)
                        acc[mi][u] = __builtin_amdgcn_mfma_f32_16x16x32_bf16(
                            Af[mi], Bf[u], acc[mi][u], 0, 0, 0);
            }

            // mining epilogue: acc == 64*(sq_j - 2 dot)
            #pragma unroll
            for (int mi = 0; mi < 4; ++mi) {
                #pragma unroll
                for (int v = 0; v < 4; ++v) {
                    const int r   = mi * 4 + v;
                    const int trg = (tpk[mi] >> (8 * v)) & 0xFF;
                    int k0 = (int)acc[mi][0][v];
                    int k1 = (int)acc[mi][1][v];
                    int p0 = (int)(((unsigned)k0 << 13) | (unsigned)jc[0]);
                    int p1 = (int)(((unsigned)k1 << 13) | (unsigned)jc[1]);
                    int q0 = (int)(((unsigned)k0 << 13) | (unsigned)jn[0]);
                    int q1 = (int)(((unsigned)k1 << 13) | (unsigned)jn[1]);
                    bool s0 = (tj[0] == trg);
                    bool s1 = (tj[1] == trg);
                    pp[r] = imax(imax(pp[r], s0 ? p0 : I32MIN), s1 ? p1 : I32MIN);
                    nn[r] = imin(imin(nn[r], s0 ? I32MAX : q0), s1 ? I32MAX : q1);
                }
            }
        }
    }

    // reduce across the 16 tx lanes (packed compare: ties -> lowest j)
    #pragma unroll
    for (int r = 0; r < 16; ++r) {
        int p = pp[r], n = nn[r];
        #pragma unroll
        for (int m = 1; m < 16; m <<= 1) {
            p = imax(p, __shfl_xor(p, m));
            n = imin(n, __shfl_xor(n, m));
        }
        if (tx == 0) {
            int row = i0 + (r >> 2) * 16 + lh * 4 + (r & 3);
            posP[split * BN + row] = p;
            negP[split * BN + row] = n;
        }
    }
}

// ---------------- combine splits + exact f32 dp/dn + per-row loss -------------
__global__ __launch_bounds__(256) void k_fin(const float* __restrict__ emb,
                                             const int* __restrict__ posP,
                                             const int* __restrict__ negP,
                                             float* __restrict__ loss) {
    int row  = blockIdx.x * 4 + (threadIdx.x >> 6);
    int lane = threadIdx.x & 63;

    int p = I32MIN, n = I32MAX;
    if (lane < NSPLIT) {
        p = posP[lane * BN + row];
        n = negP[lane * BN + row];
    }
    #pragma unroll
    for (int m = 1; m < NSPLIT; m <<= 1) {
        p = imax(p, __shfl_xor(p, m));
        n = imin(n, __shfl_xor(n, m));
    }
    p = __shfl(p, 0); n = __shfl(n, 0);
    int bpi = 8191 - (p & 8191), bni = n & 8191;

    float2 a  = ((const float2*)(emb + (size_t)row * DK))[lane];
    float2 pv = ((const float2*)(emb + (size_t)bpi * DK))[lane];
    float2 nv = ((const float2*)(emb + (size_t)bni * DK))[lane];
    float dp = (a.x - pv.x) * (a.x - pv.x) + (a.y - pv.y) * (a.y - pv.y);
    float dn = (a.x - nv.x) * (a.x - nv.x) + (a.y - nv.y) * (a.y - nv.y);
    #pragma unroll
    for (int m = 32; m; m >>= 1) {
        dp += __shfl_xor(dp, m);
        dn += __shfl_xor(dn, m);
    }
    if (lane == 0) {
        float lo = sqrtf(dp) - sqrtf(dn) + MARGIN_F;
        loss[row] = lo > 0.f ? lo : 0.f;
    }
}

// ---------------- mean over BN losses ----------------
__global__ __launch_bounds__(256) void k_mean(const float* __restrict__ loss,
                                              float* __restrict__ out) {
    int tid = threadIdx.x;
    float s = 0.f;
    for (int q = tid; q < BN; q += 256) s += loss[q];
    #pragma unroll
    for (int m = 32; m; m >>= 1) s += __shfl_xor(s, m);
    __shared__ float wsum[4];
    if ((tid & 63) == 0) wsum[tid >> 6] = s;
    __syncthreads();
    if (tid == 0) out[0] = (wsum[0] + wsum[1] + wsum[2] + wsum[3]) * (1.0f / BN);
}

extern "C" void kernel_launch(void* const* d_in, const int* in_sizes, int n_in,
                              void* d_out, int out_size, void* d_ws, size_t ws_size,
                              hipStream_t stream) {
    const float* emb = (const float*)d_in[0];
    const int*   tgt = (const int*)d_in[1];
    float* out = (float*)d_out;

    float* wsf = (float*)d_ws;
    unsigned short* Eb  = (unsigned short*)wsf;
    unsigned short* EbS = (unsigned short*)(wsf + OFF_EBS);
    float* sq64 = wsf + OFF_SQ;
    int*   posP = (int*)(wsf + OFF_POSP);
    int*   negP = (int*)(wsf + OFF_NEGP);
    float* loss = wsf + OFF_LOSS;

    k_prep<<<BN / 4, 256, 0, stream>>>(emb, Eb, EbS, sq64);
    k_mine3<<<(BN / 64) * NSPLIT / 4, 256, 0, stream>>>(Eb, EbS, sq64, tgt, posP, negP);
    k_fin<<<BN / 4, 256, 0, stream>>>(emb, posP, negP, loss);
    k_mean<<<1, 256, 0, stream>>>(loss, out);
}

// Round 9
// 101.174 us; speedup vs baseline: 1.7300x; 1.7300x over previous
//
#include <hip/hip_runtime.h>
#include <hip/hip_bf16.h>
#include <math.h>

#define BN 8192
#define DK 128
#define NSPLIT 8
#define JR (BN / NSPLIT)    // 1024
#define NJS (JR / 64)       // 16
#define MARGIN_F 1.0f
#define I32MIN (-2147483647 - 1)
#define I32MAX 2147483647

// ---------------- workspace layout (float-slot offsets from d_ws) -------------
// Eb  : bf16 8192x128 (B-side)            = 2MB
// EbS : bf16 8192x128 scaled by -128 (A)  = 2MB
// sq64: f32 64*rowsq
// posP/negP: i32 [NSPLIT][BN] packed
// red : ull sum + uint counter (16B)
#define OFF_EBS  524288
#define OFF_SQ   1048576
#define OFF_POSP (OFF_SQ + BN)
#define OFF_NEGP (OFF_POSP + NSPLIT * BN)
#define OFF_RED  (OFF_NEGP + NSPLIT * BN)

typedef __attribute__((ext_vector_type(8))) short bf16x8;
typedef __attribute__((ext_vector_type(4))) float f32x4;

__device__ __forceinline__ unsigned short f2bf(float f) {
    __hip_bfloat16 h = __float2bfloat16(f);
    return *reinterpret_cast<unsigned short*>(&h);
}
__device__ __forceinline__ int imax(int a, int b) { return a > b ? a : b; }
__device__ __forceinline__ int imin(int a, int b) { return a < b ? a : b; }

__device__ __forceinline__ void gload_lds16(const void* g, void* s) {
    __builtin_amdgcn_global_load_lds(
        (const __attribute__((address_space(1))) void*)g,
        (__attribute__((address_space(3))) void*)s, 16, 0, 0);
}

// ---------------- prep: bf16 tables (plain + -128-scaled) + 64*rowsq ----------
__global__ __launch_bounds__(256) void k_prep(const float* __restrict__ emb,
                                              unsigned short* __restrict__ Eb,
                                              unsigned short* __restrict__ EbS,
                                              float* __restrict__ sq64) {
    int row  = blockIdx.x * 4 + (threadIdx.x >> 6);
    int lane = threadIdx.x & 63;
    float2 v = ((const float2*)(emb + (size_t)row * DK))[lane];
    ushort2 o;  o.x  = f2bf(v.x);           o.y  = f2bf(v.y);
    ushort2 os; os.x = f2bf(v.x * -128.0f); os.y = f2bf(v.y * -128.0f);
    ((ushort2*)(Eb  + (size_t)row * DK))[lane] = o;
    ((ushort2*)(EbS + (size_t)row * DK))[lane] = os;
    float s = v.x * v.x + v.y * v.y;
    #pragma unroll
    for (int m = 32; m; m >>= 1) s += __shfl_xor(s, m);
    if (lane == 0) sq64[row] = 64.0f * s;
}

// ---------------- fused MFMA Gram + batch-hard mining -------------------------
// Block = 4 waves. Waves share a 64-col B-tile (double-buffered LDS, staged via
// async global_load_lds -> zero VGPR prefetch cost); wave w owns 32 i-rows
// (A[2][4] in regs from -128-pre-scaled table). Grid 512 = 64 igroups x 8
// splits = 2 blocks/CU. (256,2): VGPR cap 128 (lesson r6/r8: min-waves=4
// forces a 64-VGPR cap -> spill catastrophe; 4 waves/SIMD needs <=64 VGPR,
// unreachable -> accept 2 waves/SIMD and kill latency with async staging).
// acc = 64*sq_j + (-128 x_i)·x_j = 64*(sq_j - 2 dot) = 64*mining-key.
// Packed-i32 mining: pos=max((k<<13)|(8191-j)), neg=min((k<<13)|j); ties->low j.
__global__ __launch_bounds__(256, 2)
void k_mine4(const unsigned short* __restrict__ Eb,
             const unsigned short* __restrict__ EbS,
             const float* __restrict__ sq64,
             const int* __restrict__ tgt,
             int* __restrict__ posP, int* __restrict__ negP) {
    __shared__ __align__(16) char Blds[2][16384];

    const int tid = threadIdx.x;
    const int w   = tid >> 6;
    const int l   = tid & 63;
    const int lh  = l >> 4;
    const int tx  = l & 15;
    const int igroup = blockIdx.x >> 3;   // 0..63
    const int split  = blockIdx.x & 7;    // 0..7
    const int i0w = igroup * 128 + w * 32;
    const int jb  = split * JR;
    const char* EbB = (const char*)Eb;

    // A fragments (32 rows per wave): row i0w + mi*16 + tx, from EbS
    bf16x8 A[2][4];
    #pragma unroll
    for (int mi = 0; mi < 2; ++mi) {
        const char* rp = (const char*)EbS + (size_t)(i0w + mi * 16 + tx) * 256 + lh * 16;
        #pragma unroll
        for (int ks = 0; ks < 4; ++ks)
            A[mi][ks] = *(const bf16x8*)(rp + ks * 64);
    }

    // packed i-targets (<64): byte v of tpk[mi] = tgt[i0w + mi*16 + lh*4 + v]
    int tpk[2];
    #pragma unroll
    for (int mi = 0; mi < 2; ++mi) {
        int4 q = *(const int4*)(tgt + i0w + mi * 16 + lh * 4);
        tpk[mi] = q.x | (q.y << 8) | (q.z << 16) | (q.w << 24);
    }

    int pp[8], nn[8];
    #pragma unroll
    for (int r = 0; r < 8; ++r) { pp[r] = I32MIN; nn[r] = I32MAX; }

    // stage 64-col B tile for step js into buffer buf (source-preswizzled:
    // LDS[row][c] = Eb[j0+row][c ^ (row&7)], c = 16B chunk; dst linear)
    auto stage = [&](int buf, int js) {
        const char* S = EbB + (size_t)(jb + js * 64) * 256;
        #pragma unroll
        for (int q = 0; q < 4; ++q) {
            int f  = tid + 256 * q;           // 0..1023
            int gr = f >> 4;                  // tile row 0..63
            int sc = (f & 15) ^ (gr & 7);     // swizzled source chunk
            gload_lds16(S + gr * 256 + sc * 16,
                        &Blds[buf][w * 1024 + q * 4096]);
        }
    };

    stage(0, 0);
    __syncthreads();   // drains vmcnt(0) lgkmcnt(0) before barrier

    for (int js = 0; js < NJS; ++js) {
        const int cur = js & 1;
        if (js + 1 < NJS) stage(cur ^ 1, js + 1);   // async prefetch, 0 VGPR

        const int j0 = jb + js * 64;
        int jn[4], tj[4]; float sqj[4];
        #pragma unroll
        for (int ni = 0; ni < 4; ++ni) {
            int j = j0 + ni * 16 + tx;
            jn[ni] = j; sqj[ni] = sq64[j]; tj[ni] = tgt[j];
        }

        f32x4 acc[2][4];
        #pragma unroll
        for (int mi = 0; mi < 2; ++mi)
            #pragma unroll
            for (int ni = 0; ni < 4; ++ni) {
                f32x4 a0 = {sqj[ni], sqj[ni], sqj[ni], sqj[ni]};
                acc[mi][ni] = a0;
            }

        const char* base = Blds[cur];
        #pragma unroll
        for (int ks = 0; ks < 4; ++ks) {
            bf16x8 Bf[4];
            #pragma unroll
            for (int ni = 0; ni < 4; ++ni) {
                int row = ni * 16 + tx;
                int c   = (ks * 4 + lh) ^ (row & 7);
                Bf[ni] = *(const bf16x8*)(base + row * 256 + c * 16);
            }
            #pragma unroll
            for (int mi = 0; mi < 2; ++mi)
                #pragma unroll
                for (int ni = 0; ni < 4; ++ni)
                    acc[mi][ni] = __builtin_amdgcn_mfma_f32_16x16x32_bf16(
                        A[mi][ks], Bf[ni], acc[mi][ni], 0, 0, 0);
        }

        // mining epilogue: acc == 64*(sq_j - 2 dot); jc = 8191-j == q^0x1FFF
        #pragma unroll
        for (int mi = 0; mi < 2; ++mi) {
            #pragma unroll
            for (int v = 0; v < 4; ++v) {
                const int r   = mi * 4 + v;
                const int trg = (tpk[mi] >> (8 * v)) & 0xFF;
                #pragma unroll
                for (int u = 0; u < 4; ++u) {
                    int k  = (int)acc[mi][u][v];
                    int qq = (int)(((unsigned)k << 13) | (unsigned)jn[u]);
                    int pq = qq ^ 0x1FFF;
                    bool s = (tj[u] == trg);
                    pp[r] = imax(pp[r], s ? pq : I32MIN);
                    nn[r] = imin(nn[r], s ? I32MAX : qq);
                }
            }
        }

        __syncthreads();   // reads of buf[cur] done in all waves; staged data complete
    }

    // reduce across the 16 tx lanes (packed compare: ties -> lowest j)
    #pragma unroll
    for (int r = 0; r < 8; ++r) {
        int p = pp[r], n = nn[r];
        #pragma unroll
        for (int m = 1; m < 16; m <<= 1) {
            p = imax(p, __shfl_xor(p, m));
            n = imin(n, __shfl_xor(n, m));
        }
        if (tx == 0) {
            int row = i0w + (r >> 2) * 16 + lh * 4 + (r & 3);
            posP[split * BN + row] = p;
            negP[split * BN + row] = n;
        }
    }
}

// ---------------- combine splits + exact f32 dp/dn + fused mean ---------------
// Fixed-point (2^-24) integer atomic sum -> bit-deterministic; last block
// (device-scope atomic counter) finalizes out[0]. red[] zeroed per launch.
__global__ __launch_bounds__(256) void k_fin2(const float* __restrict__ emb,
                                              const int* __restrict__ posP,
                                              const int* __restrict__ negP,
                                              unsigned long long* __restrict__ red,
                                              float* __restrict__ out) {
    int row  = blockIdx.x * 4 + (threadIdx.x >> 6);
    int lane = threadIdx.x & 63;

    int p = I32MIN, n = I32MAX;
    if (lane < NSPLIT) {
        p = posP[lane * BN + row];
        n = negP[lane * BN + row];
    }
    #pragma unroll
    for (int m = 1; m < NSPLIT; m <<= 1) {
        p = imax(p, __shfl_xor(p, m));
        n = imin(n, __shfl_xor(n, m));
    }
    p = __shfl(p, 0); n = __shfl(n, 0);
    int bpi = 8191 - (p & 8191), bni = n & 8191;

    float2 a  = ((const float2*)(emb + (size_t)row * DK))[lane];
    float2 pv = ((const float2*)(emb + (size_t)bpi * DK))[lane];
    float2 nv = ((const float2*)(emb + (size_t)bni * DK))[lane];
    float dp = (a.x - pv.x) * (a.x - pv.x) + (a.y - pv.y) * (a.y - pv.y);
    float dn = (a.x - nv.x) * (a.x - nv.x) + (a.y - nv.y) * (a.y - nv.y);
    #pragma unroll
    for (int m = 32; m; m >>= 1) {
        dp += __shfl_xor(dp, m);
        dn += __shfl_xor(dn, m);
    }

    __shared__ unsigned long long part[4];
    if (lane == 0) {
        float lo = sqrtf(dp) - sqrtf(dn) + MARGIN_F;
        lo = lo > 0.f ? lo : 0.f;
        part[threadIdx.x >> 6] = (unsigned long long)(lo * 16777216.0f);
    }
    __syncthreads();
    if (threadIdx.x == 0) {
        unsigned long long s = part[0] + part[1] + part[2] + part[3];
        atomicAdd(red, s);
        __threadfence();
        unsigned int t = atomicAdd((unsigned int*)(red + 1), 1u);
        if (t == gridDim.x - 1) {
            unsigned long long tot = atomicAdd(red, 0ULL);
            out[0] = (float)((double)tot / 16777216.0 / (double)BN);
        }
    }
}

extern "C" void kernel_launch(void* const* d_in, const int* in_sizes, int n_in,
                              void* d_out, int out_size, void* d_ws, size_t ws_size,
                              hipStream_t stream) {
    const float* emb = (const float*)d_in[0];
    const int*   tgt = (const int*)d_in[1];
    float* out = (float*)d_out;

    float* wsf = (float*)d_ws;
    unsigned short* Eb  = (unsigned short*)wsf;
    unsigned short* EbS = (unsigned short*)(wsf + OFF_EBS);
    float* sq64 = wsf + OFF_SQ;
    int*   posP = (int*)(wsf + OFF_POSP);
    int*   negP = (int*)(wsf + OFF_NEGP);
    unsigned long long* red = (unsigned long long*)(wsf + OFF_RED);

    hipMemsetAsync(red, 0, 16, stream);
    k_prep<<<BN / 4, 256, 0, stream>>>(emb, Eb, EbS, sq64);
    k_mine4<<<(BN / 128) * NSPLIT, 256, 0, stream>>>(Eb, EbS, sq64, tgt, posP, negP);
    k_fin2<<<BN / 4, 256, 0, stream>>>(emb, posP, negP, red, out);
}

// Round 10
// 55.311 us; speedup vs baseline: 3.1644x; 1.8292x over previous
//
#include <hip/hip_runtime.h>
#include <hip/hip_bf16.h>
#include <math.h>

#define BN 8192
#define DK 128
#define NSPLIT 8
#define JR (BN / NSPLIT)    // 1024 cols per split
#define NG (JR / 128)       // 8 groups of 128 cols (2 x 64-col halves)
#define MARGIN_F 1.0f
#define I32MIN (-2147483647 - 1)
#define I32MAX 2147483647

// ---------------- workspace layout (float-slot offsets from d_ws) -------------
// Eb  : bf16 8192x128 (B-side)            = 2MB
// EbS : bf16 8192x128 scaled by -128 (A)  = 2MB
// sq64: f32 64*rowsq
// posP/negP: i32 [NSPLIT][BN] packed
// loss: f32 [BN]
#define OFF_EBS  524288
#define OFF_SQ   1048576
#define OFF_POSP (OFF_SQ + BN)
#define OFF_NEGP (OFF_POSP + NSPLIT * BN)
#define OFF_LOSS (OFF_NEGP + NSPLIT * BN)

typedef __attribute__((ext_vector_type(8))) short bf16x8;
typedef __attribute__((ext_vector_type(4))) float f32x4;

__device__ __forceinline__ unsigned short f2bf(float f) {
    __hip_bfloat16 h = __float2bfloat16(f);
    return *reinterpret_cast<unsigned short*>(&h);
}
__device__ __forceinline__ int imax(int a, int b) { return a > b ? a : b; }
__device__ __forceinline__ int imin(int a, int b) { return a < b ? a : b; }

__device__ __forceinline__ void gload_lds16(const void* g, void* s) {
    __builtin_amdgcn_global_load_lds(
        (const __attribute__((address_space(1))) void*)g,
        (__attribute__((address_space(3))) void*)s, 16, 0, 0);
}

// ---------------- prep: bf16 tables (plain + -128-scaled) + 64*rowsq ----------
__global__ __launch_bounds__(256) void k_prep(const float* __restrict__ emb,
                                              unsigned short* __restrict__ Eb,
                                              unsigned short* __restrict__ EbS,
                                              float* __restrict__ sq64) {
    int row  = blockIdx.x * 4 + (threadIdx.x >> 6);
    int lane = threadIdx.x & 63;
    float2 v = ((const float2*)(emb + (size_t)row * DK))[lane];
    ushort2 o;  o.x  = f2bf(v.x);           o.y  = f2bf(v.y);
    ushort2 os; os.x = f2bf(v.x * -128.0f); os.y = f2bf(v.y * -128.0f);
    ((ushort2*)(Eb  + (size_t)row * DK))[lane] = o;
    ((ushort2*)(EbS + (size_t)row * DK))[lane] = os;
    float s = v.x * v.x + v.y * v.y;
    #pragma unroll
    for (int m = 32; m; m >>= 1) s += __shfl_xor(s, m);
    if (lane == 0) sq64[row] = 64.0f * s;
}

// ---------------- fused MFMA Gram + batch-hard mining -------------------------
// Block = 4 waves sharing a 128-col B group (two 64-col subtiles) per barrier
// interval; double-buffered 2x32KB LDS staged via async global_load_lds
// (zero-VGPR prefetch). Wave w owns 32 i-rows (A[2][4] regs, -128-pre-scaled).
// Grid 512 = 64 igroups x 8 splits = 2 blocks/CU, 2 waves/SIMD (VGPR<=128;
// r6/r8 lesson: min-waves=4 forces 64-VGPR cap -> spill catastrophe).
// Barriers: one per 128 cols (8 total, was 16) -> half the vmcnt-drain stalls.
// acc = 64*sq_j + (-128 x_i)·x_j = 64*(sq_j - 2 dot) = 64*mining-key.
// Packed-i32 mining: pos=max(packed^0x1FFF), neg=min(packed); ties -> low j.
__global__ __launch_bounds__(256, 2)
void k_mine5(const unsigned short* __restrict__ Eb,
             const unsigned short* __restrict__ EbS,
             const float* __restrict__ sq64,
             const int* __restrict__ tgt,
             int* __restrict__ posP, int* __restrict__ negP) {
    __shared__ __align__(16) char Blds[2][2][16384];   // [buf][half][16KB]

    const int tid = threadIdx.x;
    const int w   = tid >> 6;
    const int l   = tid & 63;
    const int lh  = l >> 4;
    const int tx  = l & 15;
    const int igroup = blockIdx.x >> 3;   // 0..63
    const int split  = blockIdx.x & 7;    // 0..7
    const int i0w = igroup * 128 + w * 32;
    const int jb  = split * JR;
    const char* EbB = (const char*)Eb;

    // A fragments (32 rows per wave) from the -128-scaled table
    bf16x8 A[2][4];
    #pragma unroll
    for (int mi = 0; mi < 2; ++mi) {
        const char* rp = (const char*)EbS + (size_t)(i0w + mi * 16 + tx) * 256 + lh * 16;
        #pragma unroll
        for (int ks = 0; ks < 4; ++ks)
            A[mi][ks] = *(const bf16x8*)(rp + ks * 64);
    }

    // packed i-targets (<64): byte v of tpk[mi] = tgt[i0w + mi*16 + lh*4 + v]
    int tpk[2];
    #pragma unroll
    for (int mi = 0; mi < 2; ++mi) {
        int4 q = *(const int4*)(tgt + i0w + mi * 16 + lh * 4);
        tpk[mi] = q.x | (q.y << 8) | (q.z << 16) | (q.w << 24);
    }

    int pp[8], nn[8];
    #pragma unroll
    for (int r = 0; r < 8; ++r) { pp[r] = I32MIN; nn[r] = I32MAX; }

    // stage one 64-col subtile (16KB), source-preswizzled:
    // LDS[row][c] = Eb[j0+row][c ^ (row&7)], c = 16B chunk; dst linear.
    auto stage64 = [&](char* dst, int jcol0) {
        const char* S = EbB + (size_t)jcol0 * 256;
        #pragma unroll
        for (int q = 0; q < 4; ++q) {
            int f  = tid + 256 * q;           // 0..1023
            int gr = f >> 4;                  // subtile row 0..63
            int sc = (f & 15) ^ (gr & 7);     // swizzled source chunk
            gload_lds16(S + gr * 256 + sc * 16, dst + w * 1024 + q * 4096);
        }
    };

    stage64(Blds[0][0], jb);
    stage64(Blds[0][1], jb + 64);
    __syncthreads();   // compiler drains vmcnt before barrier

    for (int g = 0; g < NG; ++g) {
        const int buf = g & 1;
        if (g + 1 < NG) {                       // async prefetch next 128 cols
            stage64(Blds[buf ^ 1][0], jb + (g + 1) * 128);
            stage64(Blds[buf ^ 1][1], jb + (g + 1) * 128 + 64);
        }

        #pragma unroll
        for (int s = 0; s < 2; ++s) {
            const int j0 = jb + g * 128 + s * 64;
            int jn[4], tj[4]; float sqj[4];
            #pragma unroll
            for (int ni = 0; ni < 4; ++ni) {
                int j = j0 + ni * 16 + tx;
                jn[ni] = j; sqj[ni] = sq64[j]; tj[ni] = tgt[j];
            }

            f32x4 acc[2][4];
            #pragma unroll
            for (int mi = 0; mi < 2; ++mi)
                #pragma unroll
                for (int ni = 0; ni < 4; ++ni) {
                    f32x4 a0 = {sqj[ni], sqj[ni], sqj[ni], sqj[ni]};
                    acc[mi][ni] = a0;
                }

            const char* base = Blds[buf][s];
            #pragma unroll
            for (int ks = 0; ks < 4; ++ks) {
                bf16x8 Bf[4];
                #pragma unroll
                for (int ni = 0; ni < 4; ++ni) {
                    int row = ni * 16 + tx;
                    int c   = (ks * 4 + lh) ^ (row & 7);
                    Bf[ni] = *(const bf16x8*)(base + row * 256 + c * 16);
                }
                #pragma unroll
                for (int mi = 0; mi < 2; ++mi)
                    #pragma unroll
                    for (int ni = 0; ni < 4; ++ni)
                        acc[mi][ni] = __builtin_amdgcn_mfma_f32_16x16x32_bf16(
                            A[mi][ks], Bf[ni], acc[mi][ni], 0, 0, 0);
            }

            // mining epilogue: acc == 64*(sq_j - 2 dot)
            #pragma unroll
            for (int mi = 0; mi < 2; ++mi) {
                #pragma unroll
                for (int v = 0; v < 4; ++v) {
                    const int r   = mi * 4 + v;
                    const int trg = (tpk[mi] >> (8 * v)) & 0xFF;
                    #pragma unroll
                    for (int u = 0; u < 4; ++u) {
                        int k  = (int)acc[mi][u][v];
                        int qq = (int)(((unsigned)k << 13) | (unsigned)jn[u]);
                        int pq = qq ^ 0x1FFF;     // == (k<<13)|(8191-j)
                        bool ss = (tj[u] == trg);
                        pp[r] = imax(pp[r], ss ? pq : I32MIN);
                        nn[r] = imin(nn[r], ss ? I32MAX : qq);
                    }
                }
            }
        }

        __syncthreads();   // all waves done reading buf; prefetch complete
    }

    // reduce across the 16 tx lanes (packed compare: ties -> lowest j)
    #pragma unroll
    for (int r = 0; r < 8; ++r) {
        int p = pp[r], n = nn[r];
        #pragma unroll
        for (int m = 1; m < 16; m <<= 1) {
            p = imax(p, __shfl_xor(p, m));
            n = imin(n, __shfl_xor(n, m));
        }
        if (tx == 0) {
            int row = i0w + (r >> 2) * 16 + lh * 4 + (r & 3);
            posP[split * BN + row] = p;
            negP[split * BN + row] = n;
        }
    }
}

// ---------------- combine splits + exact f32 dp/dn + per-row loss -------------
__global__ __launch_bounds__(256) void k_fin(const float* __restrict__ emb,
                                             const int* __restrict__ posP,
                                             const int* __restrict__ negP,
                                             float* __restrict__ loss) {
    int row  = blockIdx.x * 4 + (threadIdx.x >> 6);
    int lane = threadIdx.x & 63;

    int p = I32MIN, n = I32MAX;
    if (lane < NSPLIT) {
        p = posP[lane * BN + row];
        n = negP[lane * BN + row];
    }
    #pragma unroll
    for (int m = 1; m < NSPLIT; m <<= 1) {
        p = imax(p, __shfl_xor(p, m));
        n = imin(n, __shfl_xor(n, m));
    }
    p = __shfl(p, 0); n = __shfl(n, 0);
    int bpi = 8191 - (p & 8191), bni = n & 8191;

    float2 a  = ((const float2*)(emb + (size_t)row * DK))[lane];
    float2 pv = ((const float2*)(emb + (size_t)bpi * DK))[lane];
    float2 nv = ((const float2*)(emb + (size_t)bni * DK))[lane];
    float dp = (a.x - pv.x) * (a.x - pv.x) + (a.y - pv.y) * (a.y - pv.y);
    float dn = (a.x - nv.x) * (a.x - nv.x) + (a.y - nv.y) * (a.y - nv.y);
    #pragma unroll
    for (int m = 32; m; m >>= 1) {
        dp += __shfl_xor(dp, m);
        dn += __shfl_xor(dn, m);
    }
    if (lane == 0) {
        float lo = sqrtf(dp) - sqrtf(dn) + MARGIN_F;
        loss[row] = lo > 0.f ? lo : 0.f;
    }
}

// ---------------- mean over BN losses ----------------
__global__ __launch_bounds__(256) void k_mean(const float* __restrict__ loss,
                                              float* __restrict__ out) {
    int tid = threadIdx.x;
    float s = 0.f;
    for (int q = tid; q < BN; q += 256) s += loss[q];
    #pragma unroll
    for (int m = 32; m; m >>= 1) s += __shfl_xor(s, m);
    __shared__ float wsum[4];
    if ((tid & 63) == 0) wsum[tid >> 6] = s;
    __syncthreads();
    if (tid == 0) out[0] = (wsum[0] + wsum[1] + wsum[2] + wsum[3]) * (1.0f / BN);
}

extern "C" void kernel_launch(void* const* d_in, const int* in_sizes, int n_in,
                              void* d_out, int out_size, void* d_ws, size_t ws_size,
                              hipStream_t stream) {
    const float* emb = (const float*)d_in[0];
    const int*   tgt = (const int*)d_in[1];
    float* out = (float*)d_out;

    float* wsf = (float*)d_ws;
    unsigned short* Eb  = (unsigned short*)wsf;
    unsigned short* EbS = (unsigned short*)(wsf + OFF_EBS);
    float* sq64 = wsf + OFF_SQ;
    int*   posP = (int*)(wsf + OFF_POSP);
    int*   negP = (int*)(wsf + OFF_NEGP);
    float* loss = wsf + OFF_LOSS;

    k_prep<<<BN / 4, 256, 0, stream>>>(emb, Eb, EbS, sq64);
    k_mine5<<<(BN / 128) * NSPLIT, 256, 0, stream>>>(Eb, EbS, sq64, tgt, posP, negP);
    k_fin<<<BN / 4, 256, 0, stream>>>(emb, posP, negP, loss);
    k_mean<<<1, 256, 0, stream>>>(loss, out);
}